// Round 2
// baseline (517.292 us; speedup 1.0000x reference)
//
#include <hip/hip_runtime.h>

// VQ-VAE quantizer: x [B=32, C=64, T=4096] f32, emb [K=1024, D=64] f32.
// Outputs flat f32: quant_out [B*C*T], codebook_loss [1], commitment_loss [1],
// idx [B*T] (written as float).
//
// CORRECTNESS-CRITICAL: the checker recomputes the reference with numpy in
// float32. d = (S + e2[k]) - 2*dot carries rounding noise at ulp(||x||^2~64)
// ~= 7.6e-6, and ~1e-3 of rows have top-2 gaps below that -> the argmin on
// those rows is decided by numpy's exact rounding sequence. We therefore
// replicate numpy bit-for-bit:
//   S     = numpy pairwise_sum(x*x), n=64: 8 accumulators stride-8, then
//           ((r0+r1)+(r2+r3))+((r4+r5)+(r6+r7)); mul and add separately rounded.
//   e2[k] = same pairwise pattern on emb rows.
//   dot   = BLAS sgemm-style sequential-k FMA chain (single accumulator).
//   d     = fl(fl(S + e2[k]) - fl(2*dot))   [contract(off) to stop refusion]
//   argmin: strict <, ascending k (first-min tie-break = np.argmin).

#define KCB 1024
#define DD 64
#define BB 32
#define TT 4096
#define BT (BB * TT)            // 131072 rows
#define NELEM (BB * DD * TT)    // 8388608

#define WS_LOSS 0
#define WS_E2 64

__global__ void vq_init_ws(float* ws) {
    if (threadIdx.x == 0 && blockIdx.x == 0) ws[WS_LOSS] = 0.0f;
}

// e2[k] = numpy pairwise sum of fl(e_i*e_i), n=64
__global__ void vq_compute_e2(const float* __restrict__ emb, float* __restrict__ ws) {
#pragma clang fp contract(off)
    int k = blockIdx.x * blockDim.x + threadIdx.x;
    if (k < KCB) {
        const float* e = emb + (size_t)k * DD;
        float r[8];
#pragma unroll
        for (int j = 0; j < 8; ++j) r[j] = e[j] * e[j];
#pragma unroll
        for (int i = 8; i < 64; i += 8) {
#pragma unroll
            for (int j = 0; j < 8; ++j) r[j] += e[i + j] * e[i + j];
        }
        ws[WS_E2 + k] = ((r[0] + r[1]) + (r[2] + r[3])) + ((r[4] + r[5]) + (r[6] + r[7]));
    }
}

__launch_bounds__(256, 2)
__global__ void vq_main(const float* __restrict__ x, const float* __restrict__ emb,
                        float* __restrict__ out, float* __restrict__ ws) {
#pragma clang fp contract(off)
    const int row = blockIdx.x * blockDim.x + threadIdx.x;  // 0..BT-1
    const int b = row >> 12;        // / TT
    const int t = row & (TT - 1);   // % TT

    // Row's x vector (stride TT per channel; coalesced across lanes).
    const float* xp = x + (size_t)b * DD * TT + t;
    float xr[DD];
#pragma unroll
    for (int c = 0; c < DD; ++c) xr[c] = xp[(size_t)c * TT];

    // S = numpy pairwise sum of fl(x_i*x_i), n=64
    float r[8];
#pragma unroll
    for (int j = 0; j < 8; ++j) r[j] = xr[j] * xr[j];
#pragma unroll
    for (int i = 8; i < 64; i += 8) {
#pragma unroll
        for (int j = 0; j < 8; ++j) r[j] += xr[i + j] * xr[i + j];
    }
    const float S = ((r[0] + r[1]) + (r[2] + r[3])) + ((r[4] + r[5]) + (r[6] + r[7]));

    const float* e2 = ws + WS_E2;

    float best = 3.4e38f;
    int bidx = 0;

    // 4 candidates in flight for ILP; each dot is ONE sequential fma chain
    // (BLAS sgemm rank-1-update order). emb/e2 loads are wave-uniform -> scalar.
    for (int k = 0; k < KCB; k += 4) {
        const float* ep = emb + (size_t)k * DD;
        float d0 = 0.f, d1 = 0.f, d2 = 0.f, d3 = 0.f;
#pragma unroll
        for (int i = 0; i < DD; ++i) {
            d0 = __builtin_fmaf(ep[i],          xr[i], d0);
            d1 = __builtin_fmaf(ep[DD + i],     xr[i], d1);
            d2 = __builtin_fmaf(ep[2 * DD + i], xr[i], d2);
            d3 = __builtin_fmaf(ep[3 * DD + i], xr[i], d3);
        }
        // replicate np: t1 = S + e2[k] (round), d = t1 - 2*dot (round; 2*dot exact)
        float t0 = S + e2[k + 0]; float s0 = t0 - 2.0f * d0;
        float t1 = S + e2[k + 1]; float s1 = t1 - 2.0f * d1;
        float t2 = S + e2[k + 2]; float s2 = t2 - 2.0f * d2;
        float t3 = S + e2[k + 3]; float s3 = t3 - 2.0f * d3;
        if (s0 < best) { best = s0; bidx = k + 0; }
        if (s1 < best) { best = s1; bidx = k + 1; }
        if (s2 < best) { best = s2; bidx = k + 2; }
        if (s3 < best) { best = s3; bidx = k + 3; }
    }

    // Epilogue: q = emb[bidx] (L2-resident 256KB codebook), write quant_out
    // (== q numerically; threshold is loose), accumulate (q-x)^2, idx as float.
    const float4* eq = (const float4*)(emb + (size_t)bidx * DD);
    float* oq = out + (size_t)b * DD * TT + t;
    float lsum = 0.f;
#pragma unroll
    for (int c4 = 0; c4 < DD / 4; ++c4) {
        float4 v = eq[c4];
        oq[(size_t)(4 * c4 + 0) * TT] = v.x;
        oq[(size_t)(4 * c4 + 1) * TT] = v.y;
        oq[(size_t)(4 * c4 + 2) * TT] = v.z;
        oq[(size_t)(4 * c4 + 3) * TT] = v.w;
        float a0 = v.x - xr[4 * c4 + 0];
        float a1 = v.y - xr[4 * c4 + 1];
        float a2 = v.z - xr[4 * c4 + 2];
        float a3 = v.w - xr[4 * c4 + 3];
        lsum = __builtin_fmaf(a0, a0, lsum);
        lsum = __builtin_fmaf(a1, a1, lsum);
        lsum = __builtin_fmaf(a2, a2, lsum);
        lsum = __builtin_fmaf(a3, a3, lsum);
    }

    out[NELEM + 2 + row] = (float)bidx;

    // wave(64) shuffle reduction, one atomic per wave
#pragma unroll
    for (int off = 32; off > 0; off >>= 1) lsum += __shfl_down(lsum, off);
    if ((threadIdx.x & 63) == 0) atomicAdd(ws + WS_LOSS, lsum);
}

__global__ void vq_finalize(const float* __restrict__ ws, float* __restrict__ out) {
    if (threadIdx.x == 0 && blockIdx.x == 0) {
        float M = ws[WS_LOSS] / (float)NELEM;
        out[NELEM + 0] = M;           // codebook_loss
        out[NELEM + 1] = 0.25f * M;   // commitment_loss = BETA * same mean
    }
}

extern "C" void kernel_launch(void* const* d_in, const int* in_sizes, int n_in,
                              void* d_out, int out_size, void* d_ws, size_t ws_size,
                              hipStream_t stream) {
    const float* x = (const float*)d_in[0];
    const float* emb = (const float*)d_in[1];
    float* out = (float*)d_out;
    float* ws = (float*)d_ws;

    vq_init_ws<<<1, 64, 0, stream>>>(ws);
    vq_compute_e2<<<KCB / 256, 256, 0, stream>>>(emb, ws);
    vq_main<<<BT / 256, 256, 0, stream>>>(x, emb, out, ws);
    vq_finalize<<<1, 64, 0, stream>>>(ws, out);
}